// Round 13
// baseline (904.644 us; speedup 1.0000x reference)
//
#include <hip/hip_runtime.h>
#include <hip/hip_fp16.h>
#include <math.h>

#define HDIM 128

#define BSHIFT 7
#define BW 128                  // nodes per bucket (dst >> 7)
#define BCAP 4096               // slots per bucket
#define NBKMAX 1024
#define CHUNK 4096              // edges per bucket_bin block

typedef __attribute__((ext_vector_type(8))) _Float16 f16x8;
typedef __attribute__((ext_vector_type(2))) _Float16 f16x2;
typedef __attribute__((ext_vector_type(16))) float f32x16;
typedef unsigned int uint32;
typedef unsigned short u16;

// packed fp16 max -> v_pk_max_f16
__device__ __forceinline__ uint32 hmax2u(uint32 a, uint32 b) {
    f16x2 ha = __builtin_bit_cast(f16x2, a);
    f16x2 hb = __builtin_bit_cast(f16x2, b);
    f16x2 r = __builtin_elementwise_max(ha, hb);
    return __builtin_bit_cast(uint32, r);
}
// packed fp16 add -> v_pk_add_f16
__device__ __forceinline__ uint32 hadd2u(uint32 a, uint32 b) {
    f16x2 ha = __builtin_bit_cast(f16x2, a);
    f16x2 hb = __builtin_bit_cast(f16x2, b);
    f16x2 r = ha + hb;
    return __builtin_bit_cast(uint32, r);
}

// ---------------- CSR build: bucketed two-pass (write-amp ~1) ----------------

__global__ __launch_bounds__(256) void bucket_bin(
    const int* __restrict__ ei, int E_, int nbk,
    int* __restrict__ bucketCnt, uint32* __restrict__ tmp)
{
    __shared__ int cnt[NBKMAX];
    __shared__ int gbase[NBKMAX];
    const int t = threadIdx.x;
    const int start = blockIdx.x * CHUNK;
    const int end = min(start + CHUNK, E_);

    for (int i = t; i < nbk; i += 256) cnt[i] = 0;
    __syncthreads();
    for (int e = start + t; e < end; e += 256)
        atomicAdd(&cnt[ei[E_ + e] >> BSHIFT], 1);
    __syncthreads();
    for (int i = t; i < nbk; i += 256) {
        int c = cnt[i];
        gbase[i] = c ? atomicAdd(&bucketCnt[i], c) : 0;
    }
    __syncthreads();
    for (int i = t; i < nbk; i += 256) cnt[i] = 0;
    __syncthreads();
    for (int e = start + t; e < end; e += 256) {
        int d = ei[E_ + e];
        int s = ei[e];
        int b = d >> BSHIFT;
        int r = atomicAdd(&cnt[b], 1);
        tmp[(size_t)b * BCAP + gbase[b] + r] =
            ((uint32)(d & (BW - 1)) << 17) | (uint32)s;
    }
}

__global__ __launch_bounds__(1024) void bucket_scan(
    const int* __restrict__ bucketCnt, int* __restrict__ bucketBase,
    int nbk, int* __restrict__ off, int N_, int E_) {
    __shared__ int sd[1024];
    int t = threadIdx.x;
    int v = (t < nbk) ? bucketCnt[t] : 0;
    sd[t] = v;
    __syncthreads();
    for (int ofs = 1; ofs < 1024; ofs <<= 1) {
        int add = (t >= ofs) ? sd[t - ofs] : 0;
        __syncthreads();
        sd[t] += add;
        __syncthreads();
    }
    if (t < nbk) bucketBase[t] = sd[t] - v;
    if (t == 0) off[N_] = E_;
}

__global__ __launch_bounds__(256) void bucket_csr(
    const uint32* __restrict__ tmp, const int* __restrict__ bucketCnt,
    const int* __restrict__ bucketBase,
    int* __restrict__ off, int* __restrict__ srcs, int N_)
{
    __shared__ int lc[BW];
    __shared__ int lo[BW];
    __shared__ int sd[256];
    const int b = blockIdx.x, t = threadIdx.x;
    const int cnt = bucketCnt[b], base = bucketBase[b];
    const uint32* tp = tmp + (size_t)b * BCAP;

    if (t < BW) lc[t] = 0;
    __syncthreads();
    for (int i = t; i < cnt; i += 256) atomicAdd(&lc[tp[i] >> 17], 1);
    __syncthreads();

    int v = (t < BW) ? lc[t] : 0;
    sd[t] = v;
    __syncthreads();
    for (int ofs = 1; ofs < 256; ofs <<= 1) {
        int add = (t >= ofs) ? sd[t - ofs] : 0;
        __syncthreads();
        sd[t] += add;
        __syncthreads();
    }
    if (t < BW) lo[t] = sd[t] - v;
    __syncthreads();

    for (int i = t; i < BW; i += 256) {
        int node = b * BW + i;
        if (node < N_) off[node] = base + lo[i];
    }
    if (t < BW) lc[t] = lo[t];
    __syncthreads();
    for (int i = t; i < cnt; i += 256) {
        uint32 p = tp[i];
        int dl = p >> 17, s = p & 0x1FFFF;
        int pos = base + atomicAdd(&lc[dl], 1);
        srcs[pos] = s;
    }
}

// ---------------- casts ----------------

__global__ void cast_x(const float* __restrict__ x, uint32* __restrict__ xb, int n2) {
    int i = blockIdx.x * 256 + threadIdx.x;
    if (i >= n2) return;
    float2 v = ((const float2*)x)[i];
    f16x2 h = { (_Float16)v.x, (_Float16)v.y };
    xb[i] = __builtin_bit_cast(uint32, h);
}

// pack weights into frag-major layout: PW[layer][(g*16+ks)*64+lane] = 16B frag
__global__ void cast_weights_packed(
    const float* __restrict__ W1l, const float* __restrict__ W1r,
    const float* __restrict__ W2l, const float* __restrict__ W2r,
    const float* __restrict__ W3l, const float* __restrict__ W3r,
    f16x8* __restrict__ PW)
{
    int tid = blockIdx.x * 256 + threadIdx.x;   // 3*4096 frags
    if (tid >= 3 * 4096) return;
    int layer = tid >> 12, rem = tid & 4095;
    int g = rem >> 10, ks = (rem >> 6) & 15, lane = rem & 63;
    int col = g * 32 + (lane & 31), kq = lane >> 5;
    const float* src;
    if (layer == 0)      src = (ks < 8) ? W1l : W1r;
    else if (layer == 1) src = (ks < 8) ? W2l : W2r;
    else                 src = (ks < 8) ? W3l : W3r;
    int kk = (ks & 7) * 16 + kq * 8;
    f16x8 v;
#pragma unroll
    for (int j = 0; j < 8; ++j) v[j] = (_Float16)src[col * HDIM + kk + j];
    PW[tid] = v;
}

// ---------------- gather-max: XCD-partitioned by feature chunk ----------------
// blockIdx&7 = feature chunk (16 feats = 32 B/row). With round-robin block->XCD
// dispatch, XCD c only touches chunk c: working set 3.2 MB < 4 MiB L2-resident.
// 1 wave/node: 16 edge slots x 4 lanes x uint2(8 B).

__global__ __launch_bounds__(256) void gather_max(
    const uint32* __restrict__ hb,   // [Np,64] packed half2
    uint32* __restrict__ mb,         // [Np,64] packed half2
    const int* __restrict__ off, const int* __restrict__ srcs, int n_nodes)
{
    const int chunk = blockIdx.x & 7;
    const int ng = blockIdx.x >> 3;
    const int w = threadIdx.x >> 6, lane = threadIdx.x & 63;
    const int node = ng * 4 + w;
    if (node >= n_nodes) return;
    const int q = lane & 3;          // 8B sub-chunk within the 32B chunk
    const int es = lane >> 2;        // edge slot 0..15
    const int e0 = off[node], e1 = off[node + 1];
    const uint2* hp = (const uint2*)hb;   // 32 uint2 per row
    const int coff = chunk * 4 + q;

    const uint32 NINF = 0xFC00FC00u;      // half2(-inf,-inf)
    uint32 m0 = NINF, m1 = NINF;

    int e = e0 + es;
    for (; e + 16 < e1; e += 32) {        // 2 rows in flight per lane
        int s0 = srcs[e], s1 = srcs[e + 16];
        uint2 v0 = hp[(size_t)s0 * 32 + coff];
        uint2 v1 = hp[(size_t)s1 * 32 + coff];
        m0 = hmax2u(m0, v0.x); m1 = hmax2u(m1, v0.y);
        m0 = hmax2u(m0, v1.x); m1 = hmax2u(m1, v1.y);
    }
    if (e < e1) {
        uint2 v0 = hp[(size_t)srcs[e] * 32 + coff];
        m0 = hmax2u(m0, v0.x); m1 = hmax2u(m1, v0.y);
    }

    // reduce across 16 edge slots (lane bits 2..5)
    m0 = hmax2u(m0, __shfl_xor(m0, 4));  m1 = hmax2u(m1, __shfl_xor(m1, 4));
    m0 = hmax2u(m0, __shfl_xor(m0, 8));  m1 = hmax2u(m1, __shfl_xor(m1, 8));
    m0 = hmax2u(m0, __shfl_xor(m0, 16)); m1 = hmax2u(m1, __shfl_xor(m1, 16));
    m0 = hmax2u(m0, __shfl_xor(m0, 32)); m1 = hmax2u(m1, __shfl_xor(m1, 32));

    if (es == 0) {
        uint2 r = make_uint2(0u, 0u);
        if (e1 > e0) { r.x = m0; r.y = m1; }
        ((uint2*)mb)[(size_t)node * 32 + coff] = r;
    }
}

// ---------------- dense GEMM: swizzled-LDS A-tile + packed B-frags ----------------

#define ESTRIDE 136   // halves per row in epilogue LDS

__global__ __launch_bounds__(256) void gemm_layer(
    const uint4* __restrict__ mb, const uint4* __restrict__ hb,
    const uint4* __restrict__ res, uint4* __restrict__ outb,
    const uint4* __restrict__ PW,       // [4096] packed frags for this layer
    const float* __restrict__ bias, int n_nodes)
{
    __shared__ uint4 sm[512];             // m-tile: 32 rows x 16 chunks (8 KiB)
    __shared__ uint4 sh[512];             // h-tile
    __shared__ _Float16 ho[32 * ESTRIDE]; // epilogue transpose (8.5 KiB)
    const int t = threadIdx.x, lane = t & 63, w = t >> 6;
    const int base = blockIdx.x * 32;
    const int l31 = lane & 31, kq = lane >> 5;

#pragma unroll
    for (int r = 0; r < 2; ++r) {
        int g = r * 256 + t;            // 0..511
        int row = g >> 4, ch = g & 15;
        int sw = ch ^ (row & 7);
        size_t gi = (size_t)(base + row) * 16 + ch;
        sm[row * 16 + sw] = mb[gi];
        sh[row * 16 + sw] = hb[gi];
    }
    __syncthreads();

    f32x16 acc = {};

#pragma unroll
    for (int k = 0; k < 8; ++k) {   // m half, K=0..127
        f16x8 a = __builtin_bit_cast(f16x8, sm[l31 * 16 + ((2 * k + kq) ^ (l31 & 7))]);
        f16x8 b = __builtin_bit_cast(f16x8, PW[(w * 16 + k) * 64 + lane]);
        acc = __builtin_amdgcn_mfma_f32_32x32x16_f16(a, b, acc, 0, 0, 0);
    }
#pragma unroll
    for (int k = 0; k < 8; ++k) {   // h half, K=128..255
        f16x8 a = __builtin_bit_cast(f16x8, sh[l31 * 16 + ((2 * k + kq) ^ (l31 & 7))]);
        f16x8 b = __builtin_bit_cast(f16x8, PW[(w * 16 + 8 + k) * 64 + lane]);
        acc = __builtin_amdgcn_mfma_f32_32x32x16_f16(a, b, acc, 0, 0, 0);
    }

    // epilogue phase 1: bias + ELU in fp32, fp16 into LDS transpose tile
    const int C = w * 32 + l31;
    const float bv = bias[C];
#pragma unroll
    for (int r = 0; r < 16; ++r) {
        int row = (r & 3) + 8 * (r >> 2) + 4 * kq;
        float v = acc[r] + bv;
        v = (v > 0.f) ? v : (__expf(v) - 1.f);
        ho[row * ESTRIDE + C] = (_Float16)v;
    }
    __syncthreads();

    // epilogue phase 2: row-major uint4 out (+ packed fp16 residual)
#pragma unroll
    for (int r = 0; r < 2; ++r) {
        int g = r * 256 + t;            // 0..511
        int row = g >> 4, ch = g & 15;
        int R = base + row;
        if (R >= n_nodes) continue;
        uint4 v = *(const uint4*)&ho[row * ESTRIDE + ch * 8];
        if (res) {
            uint4 rv = res[(size_t)R * 16 + ch];
            v.x = hadd2u(v.x, rv.x); v.y = hadd2u(v.y, rv.y);
            v.z = hadd2u(v.z, rv.z); v.w = hadd2u(v.w, rv.w);
        }
        outb[(size_t)R * 16 + ch] = v;
    }
}

// ---------------- readout: sigmoid(h3 . Wo + bo), h3 in fp16 ----------------

__global__ __launch_bounds__(256) void readout(
    const uint32* __restrict__ h, const float* __restrict__ Wo,
    const float* __restrict__ bo, float* __restrict__ out, int n_nodes)
{
    int t = threadIdx.x;
    int n = t >> 4, l = t & 15;
    int node = blockIdx.x * 16 + n;
    if (node >= n_nodes) return;
    float s = 0.f;
    for (int j = l; j < 64; j += 16) {
        uint32 v = h[(size_t)node * 64 + j];
        f16x2 hh = __builtin_bit_cast(f16x2, v);
        s += (float)hh.x * Wo[2 * j] + (float)hh.y * Wo[2 * j + 1];
    }
    for (int o = 8; o; o >>= 1) s += __shfl_down(s, o, 16);
    if (l == 0) out[node] = 1.f / (1.f + expf(-(s + bo[0])));
}

// ---------------- launch ----------------

extern "C" void kernel_launch(void* const* d_in, const int* in_sizes, int n_in,
                              void* d_out, int out_size, void* d_ws, size_t ws_size,
                              hipStream_t stream) {
    const float* x   = (const float*)d_in[0];
    const int*   ei  = (const int*)d_in[1];
    const float* W1l = (const float*)d_in[2];
    const float* b1  = (const float*)d_in[3];
    const float* W1r = (const float*)d_in[4];
    const float* W2l = (const float*)d_in[5];
    const float* b2  = (const float*)d_in[6];
    const float* W2r = (const float*)d_in[7];
    const float* W3l = (const float*)d_in[8];
    const float* b3  = (const float*)d_in[9];
    const float* W3r = (const float*)d_in[10];
    const float* Wo  = (const float*)d_in[11];
    const float* bo  = (const float*)d_in[12];
    float* out = (float*)d_out;

    const int N_ = in_sizes[0] / HDIM;
    const int E_ = in_sizes[1] / 2;
    const int Np = (N_ + 127) & ~127;
    const int nbk = (N_ + BW - 1) / BW;   // 782 for N=100k

    size_t o = 0;
    auto carve = [&](size_t bytes) { size_t r = o; o = (o + bytes + 255) & ~255ULL; return r; };
    char* ws = (char*)d_ws;
    int* off        = (int*)(ws + carve((size_t)(N_ + 1) * 4));
    int* bucketCnt  = (int*)(ws + carve((size_t)NBKMAX * 4));
    int* bucketBase = (int*)(ws + carve((size_t)NBKMAX * 4));
    int* srcs       = (int*)(ws + carve((size_t)E_ * 4));
    uint32* tmp     = (uint32*)(ws + carve((size_t)nbk * BCAP * 4));
    uint4* PW       = (uint4*)(ws + carve((size_t)3 * 4096 * 16));
    uint32* XB      = (uint32*)(ws + carve((size_t)Np * 64 * 4));  // x / h2
    uint32* H1B     = (uint32*)(ws + carve((size_t)Np * 64 * 4));  // h1 / h3
    uint32* MB      = (uint32*)(ws + carve((size_t)Np * 64 * 4));  // aggregated max
    (void)ws_size; (void)n_in; (void)out_size;

    // CSR build (bucketed; also produces off[])
    (void)hipMemsetAsync(bucketCnt, 0, (size_t)NBKMAX * 4, stream);
    bucket_bin<<<(E_ + CHUNK - 1) / CHUNK, 256, 0, stream>>>(ei, E_, nbk, bucketCnt, tmp);
    bucket_scan<<<1, 1024, 0, stream>>>(bucketCnt, bucketBase, nbk, off, N_, E_);
    bucket_csr<<<nbk, 256, 0, stream>>>(tmp, bucketCnt, bucketBase, off, srcs, N_);

    // casts
    cast_weights_packed<<<(3 * 4096 + 255) / 256, 256, 0, stream>>>(
        W1l, W1r, W2l, W2r, W3l, W3r, (f16x8*)PW);
    cast_x<<<(N_ * 64 + 255) / 256, 256, 0, stream>>>(x, XB, N_ * 64);

    const int nbG = ((N_ + 3) / 4) * 8;   // x8 feature chunks (XCD-partitioned)
    const int nbM = Np / 32;              // 32 rows per block, 4 waves of 32x32

    const uint4* PW1 = PW;
    const uint4* PW2 = PW + 4096;
    const uint4* PW3 = PW + 8192;

    // layer 1: h1 = elu(W1l m + b1 + W1r x)
    gather_max<<<nbG, 256, 0, stream>>>(XB, MB, off, srcs, N_);
    gemm_layer<<<nbM, 256, 0, stream>>>((const uint4*)MB, (const uint4*)XB, nullptr,
                                        (uint4*)H1B, PW1, b1, N_);
    // layer 2: h2 = elu(...) + h1  -> XB
    gather_max<<<nbG, 256, 0, stream>>>(H1B, MB, off, srcs, N_);
    gemm_layer<<<nbM, 256, 0, stream>>>((const uint4*)MB, (const uint4*)H1B, (const uint4*)H1B,
                                        (uint4*)XB, PW2, b2, N_);
    // layer 3: h3 = elu(...) + h2  -> H1B
    gather_max<<<nbG, 256, 0, stream>>>(XB, MB, off, srcs, N_);
    gemm_layer<<<nbM, 256, 0, stream>>>((const uint4*)MB, (const uint4*)XB, (const uint4*)XB,
                                        (uint4*)H1B, PW3, b3, N_);

    readout<<<(N_ + 15) / 16, 256, 0, stream>>>(H1B, Wo, bo, out, N_);
}